// Round 9
// baseline (392.572 us; speedup 1.0000x reference)
//
#include <hip/hip_runtime.h>
#include <hip/hip_fp16.h>

constexpr int KC    = 128;    // channels
constexpr int NBLK  = 2048;   // count/partition blocks (8/CU)
constexpr int CAPA  = 1024;   // per-block edge chunk cap (chunk = 980)
constexpr int CBITS = 10;     // coarse bucket = 1024 nodes
constexpr int CSZ   = 1 << CBITS;
constexpr int NBCM  = 192;    // static max coarse buckets (157 actual)

using half8   = __attribute__((ext_vector_type(8))) _Float16;
using float4v = __attribute__((ext_vector_type(4))) float;
using uint4v  = __attribute__((ext_vector_type(4))) unsigned;

// ---------------------------------------------------------------- helpers
__device__ __forceinline__ unsigned fkey(float s) {
  unsigned u = __float_as_uint(s);
  return (u & 0x80000000u) ? ~u : (u | 0x80000000u);
}

__device__ __forceinline__ void nt_store16(void* p, uint4 v) {
  uint4v w; w[0] = v.x; w[1] = v.y; w[2] = v.z; w[3] = v.w;
  __builtin_nontemporal_store(w, (uint4v*)p);
}

// ==== M1: blocks [0,NBLK) = dst+src coarse counts ; rest = scores ========
__global__ __launch_bounds__(256) void m1_cnt_scores(
    const int* __restrict__ eui, const int* __restrict__ eiu,
    unsigned* __restrict__ cnts,
    const float* __restrict__ xu, const float* __restrict__ xi,
    const float* __restrict__ pu, const float* __restrict__ pi,
    float* __restrict__ scores, unsigned* __restrict__ hist,
    __half* __restrict__ x16,
    int E, int N, int NBC, int chunk, int NTOT) {
  __shared__ unsigned hD[4 * NBCM], hS[4 * NBCM];
  int t = threadIdx.x;
  if (blockIdx.x < NBLK) {
    // ---- count role: 4 edges/thread, int4 loads, one fat iteration ----
    int blk = blockIdx.x, w = t >> 6;
    for (int b = t; b < 4 * NBCM; b += 256) { hD[b] = 0; hS[b] = 0; }
    __syncthreads();
    int lo = blk * chunk, hi = min(2 * E, lo + chunk);
    int i = lo + t * 4;
    unsigned bw = w * NBCM;
    if (i + 3 < hi) {
      int rel = i >= E;
      int j = i - rel * E;
      if (rel == (int)(i + 3 >= E) && !(j & 3)) {
        const int* e = rel ? eiu : eui;
        int4 s4 = *(const int4*)(e + j);
        int4 d4 = *(const int4*)(e + E + j);
        int rb = rel * N;
        atomicAdd(&hD[bw + ((rb + d4.x) >> CBITS)], 1u);
        atomicAdd(&hD[bw + ((rb + d4.y) >> CBITS)], 1u);
        atomicAdd(&hD[bw + ((rb + d4.z) >> CBITS)], 1u);
        atomicAdd(&hD[bw + ((rb + d4.w) >> CBITS)], 1u);
        atomicAdd(&hS[bw + ((rb + s4.x) >> CBITS)], 1u);
        atomicAdd(&hS[bw + ((rb + s4.y) >> CBITS)], 1u);
        atomicAdd(&hS[bw + ((rb + s4.z) >> CBITS)], 1u);
        atomicAdd(&hS[bw + ((rb + s4.w) >> CBITS)], 1u);
      } else {
#pragma unroll
        for (int k = 0; k < 4; ++k) {
          int ii = i + k;
          int rl = ii >= E;
          const int* e = rl ? eiu : eui;
          int jj = ii - rl * E;
          atomicAdd(&hD[bw + ((rl * N + e[E + jj]) >> CBITS)], 1u);
          atomicAdd(&hS[bw + ((rl * N + e[jj]) >> CBITS)], 1u);
        }
      }
    } else {
#pragma unroll
      for (int k = 0; k < 4; ++k) {
        int ii = i + k;
        if (ii < hi) {
          int rl = ii >= E;
          const int* e = rl ? eiu : eui;
          int jj = ii - rl * E;
          atomicAdd(&hD[bw + ((rl * N + e[E + jj]) >> CBITS)], 1u);
          atomicAdd(&hS[bw + ((rl * N + e[jj]) >> CBITS)], 1u);
        }
      }
    }
    __syncthreads();
    for (int b = t; b < NBC; b += 256) {
      cnts[(size_t)blk * NBC + b] =
          hD[b] + hD[NBCM + b] + hD[2 * NBCM + b] + hD[3 * NBCM + b];
      cnts[(size_t)NTOT + (size_t)blk * NBC + b] =
          hS[b] + hS[NBCM + b] + hS[2 * NBCM + b] + hS[3 * NBCM + b];
    }
  } else {
    // ---- scores role: quarter-wave per row, unroll x2, grid-stride ----
    int qw = t >> 4;                 // quarter-wave index in block: 0..15
    int q  = t & 15;                 // lane within quarter
    int sgrid = (int)gridDim.x - NBLK;
    int stride = sgrid * 16;
    for (int gw = (blockIdx.x - NBLK) * 16 + qw; gw < 2 * N; gw += 2 * stride) {
      int gwB = gw + stride;
      bool hasB = gwB < 2 * N;
      int relA = gw >= N, rA = gw - relA * N;
      const float* xAp = relA ? xi : xu;
      const float* pAp = relA ? pi : pu;
      const float4* xrA = (const float4*)(xAp + (size_t)rA * KC);
      float4 a0 = xrA[q * 2], a1 = xrA[q * 2 + 1];
      float4 b0, b1;
      const float* pBp = pu;
      int relB = 0;
      if (hasB) {
        relB = gwB >= N;
        int rB = gwB - relB * N;
        const float* xBp = relB ? xi : xu;
        const float4* xrB = (const float4*)(xBp + (size_t)rB * KC);
        b0 = xrB[q * 2]; b1 = xrB[q * 2 + 1];
        pBp = relB ? pi : pu;
      }
      const float4* prA = (const float4*)pAp;
      float4 pa0 = prA[q * 2], pa1 = prA[q * 2 + 1];
      {
        __half2 h0 = __floats2half2_rn(a0.x, a0.y);
        __half2 h1 = __floats2half2_rn(a0.z, a0.w);
        __half2 h2 = __floats2half2_rn(a1.x, a1.y);
        __half2 h3 = __floats2half2_rn(a1.z, a1.w);
        uint4 u; u.x = *(unsigned*)&h0; u.y = *(unsigned*)&h1;
        u.z = *(unsigned*)&h2; u.w = *(unsigned*)&h3;
        ((uint4*)(x16 + (size_t)gw * KC))[q] = u;
      }
      float sA = a0.x * pa0.x + a0.y * pa0.y + a0.z * pa0.z + a0.w * pa0.w
               + a1.x * pa1.x + a1.y * pa1.y + a1.z * pa1.z + a1.w * pa1.w;
      float sB = 0.f;
      if (hasB) {
        const float4* prB = (const float4*)pBp;
        float4 pb0 = prB[q * 2], pb1 = prB[q * 2 + 1];
        __half2 h0 = __floats2half2_rn(b0.x, b0.y);
        __half2 h1 = __floats2half2_rn(b0.z, b0.w);
        __half2 h2 = __floats2half2_rn(b1.x, b1.y);
        __half2 h3 = __floats2half2_rn(b1.z, b1.w);
        uint4 u; u.x = *(unsigned*)&h0; u.y = *(unsigned*)&h1;
        u.z = *(unsigned*)&h2; u.w = *(unsigned*)&h3;
        ((uint4*)(x16 + (size_t)gwB * KC))[q] = u;
        sB = b0.x * pb0.x + b0.y * pb0.y + b0.z * pb0.z + b0.w * pb0.w
           + b1.x * pb1.x + b1.y * pb1.y + b1.z * pb1.z + b1.w * pb1.w;
      }
#pragma unroll
      for (int off = 8; off; off >>= 1) {
        sA += __shfl_xor(sA, off, 64);
        sB += __shfl_xor(sB, off, 64);
      }
      if (q == 0) {
        scores[gw] = sA;
        atomicAdd(&hist[relA * 65536 + (fkey(sA) >> 16)], 1u);
        if (hasB) {
          scores[gwB] = sB;
          atomicAdd(&hist[relB * 65536 + (fkey(sB) >> 16)], 1u);
        }
      }
    }
  }
}

// ==== M2: blocks 0,1 = threshold bin ; rest = scan1 (shfl scan) ==========
__global__ __launch_bounds__(1024) void m2_thresh_scan1(
    const unsigned* __restrict__ cnts, unsigned* __restrict__ sc,
    unsigned* __restrict__ bsum, const unsigned* __restrict__ hist,
    unsigned* __restrict__ ctrl, int NTOT, int NBC, int SCB) {
  __shared__ __align__(16) unsigned smem[1024 + 64 + 2];
  int t = threadIdx.x;
  if (blockIdx.x < 2) {
    // ---- k_thresh role ----
    const unsigned* h = hist + blockIdx.x * 65536;
    unsigned* c = ctrl + blockIdx.x * 8;
    unsigned* csum = smem;
    unsigned* bs = smem + 1024;
    unsigned s = 0;
    int hi = 65536 - 64 * t;
    for (int b = hi - 64; b < hi; ++b) s += h[b];
    csum[t] = s;
    __syncthreads();
    for (int off = 1; off < 1024; off <<= 1) {
      unsigned add = (t >= off) ? csum[t - off] : 0;
      __syncthreads();
      csum[t] += add;
      __syncthreads();
    }
    unsigned above = (t == 0) ? 0u : csum[t - 1];
    if (csum[t] >= 128u && above < 128u) { smem[1088] = (unsigned)t; smem[1089] = above; }
    __syncthreads();
    int chi = 65536 - 64 * (int)smem[1088];
    unsigned s_above = smem[1089];
    if (t < 64) bs[t] = h[chi - 1 - t];
    __syncthreads();
    if (t < 64) {
      unsigned v = bs[t], cum = v;
#pragma unroll
      for (int off = 1; off < 64; off <<= 1) {
        unsigned u = __shfl_up(cum, off, 64);
        if (t >= off) cum += u;
      }
      unsigned prev = cum - v;
      if (s_above + cum >= 128u && s_above + prev < 128u)
        c[0] = (unsigned)(chi - 1 - t);
    }
  } else {
    // ---- scan1 role: bucket-major reorder on read, wave-shfl scan ----
    unsigned* wsum = smem;                       // 16 partials
    int vb = blockIdx.x - 2;
    int seg = vb / SCB, lb = vb % SCB;
    int li = lb * 1024 + t;
    unsigned v = 0;
    if (li < NTOT) {
      int b = li >> 11, blk = li & (NBLK - 1);   // li = b*NBLK + blk
      v = cnts[(size_t)seg * NTOT + (size_t)blk * NBC + b];
    }
    unsigned inc = v;
#pragma unroll
    for (int off = 1; off < 64; off <<= 1) {
      unsigned u = __shfl_up(inc, off, 64);
      if ((t & 63) >= off) inc += u;
    }
    int w = t >> 6;
    if ((t & 63) == 63) wsum[w] = inc;
    __syncthreads();
    unsigned wbase = 0;
#pragma unroll
    for (int j = 0; j < 16; ++j) if (j < w) wbase += wsum[j];
    if (li < NTOT) sc[(size_t)seg * NTOT + li] = wbase + inc - v;
    if (t == 1023) bsum[vb] = wbase + inc;
  }
}

// ==== M3: blocks 0,1 = scan2 (shfl) ; rest = compact =====================
__global__ __launch_bounds__(512) void m3_scan2_compact(
    unsigned* __restrict__ bsum, int nb,
    const float* __restrict__ scores, unsigned* __restrict__ ctrl,
    int* __restrict__ cand_idx, float* __restrict__ cand_val, int N) {
  __shared__ unsigned wsum[8];
  if (blockIdx.x < 2) {
    unsigned* bs = bsum + blockIdx.x * nb;
    int t = threadIdx.x;
    unsigned v = (t < nb) ? bs[t] : 0;
    unsigned inc = v;
#pragma unroll
    for (int off = 1; off < 64; off <<= 1) {
      unsigned u = __shfl_up(inc, off, 64);
      if ((t & 63) >= off) inc += u;
    }
    int w = t >> 6;
    if ((t & 63) == 63) wsum[w] = inc;
    __syncthreads();
    unsigned wbase = 0;
#pragma unroll
    for (int j = 0; j < 8; ++j) if (j < w) wbase += wsum[j];
    if (t < nb) bs[t] = wbase + inc - v;
  } else {
    int i = (blockIdx.x - 2) * 512 + threadIdx.x;
    if (i >= 2 * N) return;
    int rel = i >= N;
    float s = scores[i];
    if ((fkey(s) >> 16) >= ctrl[rel * 8]) {
      unsigned pos = atomicAdd(&ctrl[rel * 8 + 1], 1u);
      if (pos < 2048u) {
        cand_idx[rel * 2048 + pos] = i - rel * N;
        cand_val[rel * 2048 + pos] = s;
      }
    }
  }
}

// ==== M4: blocks 0,1 = exact top-k ; rest = fused dst+src partition ======
__global__ __launch_bounds__(256) void m4_topk_part(
    const int* __restrict__ eui, const int* __restrict__ eiu,
    const unsigned* __restrict__ cnts, const unsigned* __restrict__ sc,
    const unsigned* __restrict__ bsum,
    unsigned* __restrict__ recsD, unsigned short* __restrict__ recsS,
    const unsigned* __restrict__ ctrl,
    const int* __restrict__ cand_idx, const float* __restrict__ cand_val,
    const float* __restrict__ pu, const float* __restrict__ pi,
    int* __restrict__ top_idx, float* __restrict__ top_tanh,
    int E, int N, int NBC, int chunk, int NTOT, int SCB) {
  __shared__ __align__(16) char smem[16896];
  int t = threadIdx.x;
  if (blockIdx.x < 2) {
    // ---- k_topk role ----
    float* vals = (float*)smem;                 // 8192
    int*   idxs = (int*)(smem + 8192);          // 8192
    float* red  = (float*)(smem + 16384);       // 512
    int rel = blockIdx.x;
    const float* p = rel ? pi : pu;
    int n = (int)ctrl[rel * 8 + 1]; if (n > 2048) n = 2048;
    for (int i = t; i < n; i += 256) {
      vals[i] = cand_val[rel * 2048 + i];
      idxs[i] = cand_idx[rel * 2048 + i];
    }
    if (t < 128) { float pv = p[t]; red[t] = pv * pv; }
    __syncthreads();
    for (int off = 64; off; off >>= 1) {
      if (t < off) red[t] += red[t + off];
      __syncthreads();
    }
    float pn = sqrtf(red[0]) + 1e-16f;
    for (int c = t; c < n; c += 256) {
      float v = vals[c]; int id = idxs[c];
      int rank = 0;
      for (int j = 0; j < n; ++j) {
        float vj = vals[j];
        rank += (vj > v) || (vj == v && idxs[j] < id);
      }
      if (rank < KC) {
        top_idx[rel * KC + rank] = id;
        top_tanh[rel * KC + rank] = tanhf(v / pn);
      }
    }
  } else {
    // ---- k_part role (dst + src, LDS-staged, shfl scans, quad loads) ----
    unsigned* wsumD  = (unsigned*)smem;              // 16
    unsigned* wsumS  = (unsigned*)(smem + 64);       // 16
    unsigned* curD   = (unsigned*)(smem + 1024);     // 1024
    unsigned* curS   = (unsigned*)(smem + 2048);     // 1024
    unsigned* deltaD = (unsigned*)(smem + 3072);     // 1024
    unsigned* deltaS = (unsigned*)(smem + 4096);     // 1024
    unsigned* stageD = (unsigned*)(smem + 5120);     // 4096
    unsigned short* stageS = (unsigned short*)(smem + 9216);   // 2048
    unsigned char* bktD = (unsigned char*)(smem + 11264);      // 1024
    unsigned char* bktS = (unsigned char*)(smem + 12288);      // 1024
    int blk = blockIdx.x - 2;
    int lane = t & 63, w = t >> 6;
    // dst + src exclusive scans, one shared barrier
    unsigned vD = (t < NBC) ? cnts[(size_t)blk * NBC + t] : 0;
    unsigned vS = (t < NBC) ? cnts[(size_t)NTOT + (size_t)blk * NBC + t] : 0;
    unsigned incD = vD, incS = vS;
#pragma unroll
    for (int off = 1; off < 64; off <<= 1) {
      unsigned uD = __shfl_up(incD, off, 64);
      unsigned uS = __shfl_up(incS, off, 64);
      if (lane >= off) { incD += uD; incS += uS; }
    }
    if (lane == 63) { wsumD[w] = incD; wsumS[w] = incS; }
    __syncthreads();
    unsigned wbD = 0, wbS = 0;
#pragma unroll
    for (int j = 0; j < 4; ++j) if (j < w) { wbD += wsumD[j]; wbS += wsumS[j]; }
    if (t < NBC) {
      unsigned excD = wbD + incD - vD;
      curD[t] = excD;
      int li = t * NBLK + blk;
      deltaD[t] = sc[li] + bsum[li >> 10] - excD;
      unsigned excS = wbS + incS - vS;
      curS[t] = excS;
      deltaS[t] = sc[NTOT + li] + bsum[SCB + (li >> 10)] - excS;
    }
    __syncthreads();
    int lo = blk * chunk, hi = min(2 * E, lo + chunk);
    int i = lo + t * 4;
    bool quad = false;
    int relq = 0, jq = 0;
    if (i + 3 < hi) {
      relq = i >= E;
      jq = i - relq * E;
      quad = (relq == (int)(i + 3 >= E)) && !(jq & 3);
    }
    if (quad) {
      const int* e = relq ? eiu : eui;
      int4 s4 = *(const int4*)(e + jq);
      int4 d4 = *(const int4*)(e + E + jq);
      int rb = relq * N;
      int ss[4] = {s4.x, s4.y, s4.z, s4.w};
      int dd[4] = {d4.x, d4.y, d4.z, d4.w};
#pragma unroll
      for (int k = 0; k < 4; ++k) {
        int src_g = rb + ss[k];
        int dst_g = rb + dd[k];
        int bD = dst_g >> CBITS;
        unsigned pD = atomicAdd(&curD[bD], 1u);
        stageD[pD] = (unsigned)src_g | ((unsigned)(dst_g & (CSZ - 1)) << 18);
        bktD[pD] = (unsigned char)bD;
        int bS = src_g >> CBITS;
        unsigned pS = atomicAdd(&curS[bS], 1u);
        stageS[pS] = (unsigned short)(src_g & (CSZ - 1));
        bktS[pS] = (unsigned char)bS;
      }
    } else {
#pragma unroll
      for (int k = 0; k < 4; ++k) {
        int ii = i + k;
        if (ii < hi) {
          int rl = ii >= E;
          const int* e = rl ? eiu : eui;
          int jj = ii - rl * E;
          int src_g = rl * N + e[jj];
          int dst_g = rl * N + e[E + jj];
          int bD = dst_g >> CBITS;
          unsigned pD = atomicAdd(&curD[bD], 1u);
          stageD[pD] = (unsigned)src_g | ((unsigned)(dst_g & (CSZ - 1)) << 18);
          bktD[pD] = (unsigned char)bD;
          int bS = src_g >> CBITS;
          unsigned pS = atomicAdd(&curS[bS], 1u);
          stageS[pS] = (unsigned short)(src_g & (CSZ - 1));
          bktS[pS] = (unsigned char)bS;
        }
      }
    }
    __syncthreads();
    int cnt = hi - lo;
    for (int j = t; j < cnt; j += 256) {
      recsD[deltaD[bktD[j]] + j] = stageD[j];
      recsS[deltaS[bktS[j]] + j] = stageS[j];
    }
  }
}

// ==== M5: [0,NBC)=dst CSR refine ; [NBC,2NBC)=src degrees ; rest=GRU =====
__global__ __launch_bounds__(1024) void m5_refine_gru(
    const unsigned* __restrict__ sc, const unsigned* __restrict__ bsum,
    const unsigned* __restrict__ recsD, const unsigned short* __restrict__ recsS,
    int* __restrict__ ssrc, int* __restrict__ deg_dst, int* __restrict__ endp,
    int* __restrict__ deg_src,
    const float* __restrict__ xu, const float* __restrict__ xi,
    const int* __restrict__ top_idx, const float* __restrict__ top_tanh,
    const float* __restrict__ W0u, const float* __restrict__ W0i,
    const float* __restrict__ Wihu, const float* __restrict__ Wihi,
    const float* __restrict__ Whhu, const float* __restrict__ Whhi,
    const float* __restrict__ bihu, const float* __restrict__ bihi,
    const float* __restrict__ bhhu, const float* __restrict__ bhhi,
    __half* __restrict__ Wt,
    int E, int NBC, int N2, int NTOT, int SCB) {
  __shared__ __align__(16) char smem[8256];
  int t = threadIdx.x;
  if ((int)blockIdx.x < NBC) {
    // ---- dst refine: per-bucket histogram -> scan -> scatter ----
    unsigned* hist = (unsigned*)smem;            // 4096
    unsigned* cur  = (unsigned*)(smem + 4096);   // 4096
    unsigned* t16  = (unsigned*)(smem + 8192);   // 64
    int c = blockIdx.x;
    int liLo = c * NBLK;
    int lo = (int)(sc[liLo] + bsum[liLo >> 10]);
    int hi;
    if (c + 1 < NBC) {
      int liHi = (c + 1) * NBLK;
      hi = (int)(sc[liHi] + bsum[liHi >> 10]);
    } else hi = 2 * E;
    hist[t] = 0;
    __syncthreads();
    for (int j = lo + t; j < hi; j += 1024)
      atomicAdd(&hist[recsD[j] >> 18], 1u);
    __syncthreads();
    // exclusive scan over CSZ=1024 entries, one per thread
    unsigned v = hist[t];
    unsigned inc = v;
#pragma unroll
    for (int off = 1; off < 64; off <<= 1) {
      unsigned u = __shfl_up(inc, off, 64);
      if ((t & 63) >= off) inc += u;
    }
    int w = t >> 6;
    if ((t & 63) == 63) t16[w] = inc;
    __syncthreads();
    unsigned wbase = 0;
    for (int j = 0; j < 16; ++j) if (j < w) wbase += t16[j];
    unsigned exc = wbase + inc - v;
    cur[t] = exc;
    int node = c * CSZ + t;
    if (node < N2) {
      deg_dst[node] = (int)v;
      endp[node] = lo + (int)(exc + v);
    }
    __syncthreads();
    // placement; ssrc stores BYTE offsets into xw (src * 256)
    for (int j = lo + t; j < hi; j += 1024) {
      unsigned rec = recsD[j];
      unsigned pos = atomicAdd(&cur[rec >> 18], 1u);
      ssrc[lo + (int)pos] = (int)((rec & 0x3FFFFu) << 8);
    }
  } else if ((int)blockIdx.x < 2 * NBC) {
    // ---- src refine: per-bucket histogram -> degrees ----
    unsigned* hist = (unsigned*)smem;            // 4096
    int c = blockIdx.x - NBC;
    int liLo = c * NBLK;
    int lo = (int)(sc[NTOT + liLo] + bsum[SCB + (liLo >> 10)]);
    int hi;
    if (c + 1 < NBC) {
      int liHi = (c + 1) * NBLK;
      hi = (int)(sc[NTOT + liHi] + bsum[SCB + (liHi >> 10)]);
    } else hi = 2 * E;
    hist[t] = 0;
    __syncthreads();
    for (int j = lo + t; j < hi; j += 1024)
      atomicAdd(&hist[(unsigned)recsS[j]], 1u);
    __syncthreads();
    int node = c * CSZ + t;
    if (node < N2) deg_src[node] = (int)hist[t];
  } else {
    // ---- k_gru role (first 128 threads active) ----
    int gb = blockIdx.x - 2 * NBC;
    int rel = gb >> 7, c = gb & 127;
    const float* x   = rel ? xi   : xu;
    const float* W0  = rel ? W0i  : W0u;
    const float* Wih = rel ? Wihi : Wihu;
    const float* Whh = rel ? Whhi : Whhu;
    const float* bih = rel ? bihi : bihu;
    const float* bhh = rel ? bhhi : bhhu;
    float* xt = (float*)smem;
    float* w0 = (float*)(smem + 512);
    if (t < KC) {
      xt[t] = x[(size_t)top_idx[rel * KC + c] * KC + t] * top_tanh[rel * KC + c];
      w0[t] = W0[c * KC + t];
    }
    __syncthreads();
    if (t >= KC) return;
    int k = t;
    float gir = bih[k], giz = bih[KC + k], gin = bih[2 * KC + k];
    float ghr = bhh[k], ghz = bhh[KC + k], ghn = bhh[2 * KC + k];
    const float* wr = Wih + (size_t)k * KC;
    const float* wz = Wih + (size_t)(KC + k) * KC;
    const float* wn = Wih + (size_t)(2 * KC + k) * KC;
    const float* vr = Whh + (size_t)k * KC;
    const float* vz = Whh + (size_t)(KC + k) * KC;
    const float* vn = Whh + (size_t)(2 * KC + k) * KC;
    for (int j = 0; j < KC; ++j) {
      float xj = xt[j], hj = w0[j];
      gir += xj * wr[j]; giz += xj * wz[j]; gin += xj * wn[j];
      ghr += hj * vr[j]; ghz += hj * vz[j]; ghn += hj * vn[j];
    }
    float r = 1.f / (1.f + expf(-(gir + ghr)));
    float z = 1.f / (1.f + expf(-(giz + ghz)));
    float nn = tanhf(gin + r * ghn);
    float w = (1.f - z) * nn + z * w0[k];
    Wt[(size_t)rel * KC * KC + (size_t)k * KC + c] = __float2half_rn(w);
  }
}

// ---- xw = x16 @ W via MFMA f16 16x16x32, inv_s fused, fp16 out ----------
__global__ __launch_bounds__(256) void k_gemm(const __half* __restrict__ x16,
                                              const __half* __restrict__ Wt,
                                              const int* __restrict__ deg_src,
                                              __half* __restrict__ xw, int N) {
  __shared__ __half Ws[KC * KC];        // 32 KB: Wt[n][k]
  __shared__ __half outs[64 * 136];     // 17 KB staging
  int rel = (blockIdx.x * 64) >= N;
  int t = threadIdx.x;
  const uint4* wg = (const uint4*)(Wt + (size_t)rel * KC * KC);
#pragma unroll
  for (int i = 0; i < 8; ++i)
    ((uint4*)Ws)[t + 256 * i] = wg[t + 256 * i];
  __syncthreads();
  int wid = t >> 6, lane = t & 63;
  int l15 = lane & 15, quad = lane >> 4;
  int row0 = blockIdx.x * 64 + wid * 16;
  half8 a[4];
  const __half* xrow = x16 + (size_t)(row0 + l15) * KC + quad * 8;
#pragma unroll
  for (int ks = 0; ks < 4; ++ks)
    a[ks] = __builtin_nontemporal_load((const half8*)(xrow + ks * 32));
  float4v acc[8];
#pragma unroll
  for (int nt = 0; nt < 8; ++nt) {
    acc[nt] = (float4v){0.f, 0.f, 0.f, 0.f};
#pragma unroll
    for (int ks = 0; ks < 4; ++ks) {
      half8 b = *(const half8*)&Ws[(nt * 16 + l15) * KC + ks * 32 + quad * 8];
      acc[nt] = __builtin_amdgcn_mfma_f32_16x16x32_f16(a[ks], b, acc[nt], 0, 0, 0);
    }
  }
  float scv[4];
#pragma unroll
  for (int r = 0; r < 4; ++r) {
    int dg = __builtin_nontemporal_load(deg_src + row0 + quad * 4 + r);
    scv[r] = dg > 0 ? rsqrtf((float)dg) : 0.f;
  }
  __half* ob = outs + (size_t)wid * 16 * 136;
#pragma unroll
  for (int nt = 0; nt < 8; ++nt)
#pragma unroll
    for (int r = 0; r < 4; ++r)
      ob[(quad * 4 + r) * 136 + nt * 16 + l15] = __float2half_rn(acc[nt][r] * scv[r]);
  __syncthreads();
  size_t gbase = (size_t)blockIdx.x * 64 * KC;
#pragma unroll
  for (int i = 0; i < 4; ++i) {
    int idx = t + 256 * i;
    int rr = idx >> 4, cc = idx & 15;
    *(uint4*)(xw + gbase + (size_t)rr * KC + cc * 8) =
        *(const uint4*)(outs + (size_t)rr * 136 + cc * 8);
  }
}

// ---- aggregation: quarter-wave, 4-deep, nt streams, cached xw gather ----
__global__ void k_agg(const __half* __restrict__ xw, const int* __restrict__ ssrc,
                      const int* __restrict__ endp, const int* __restrict__ deg_dst,
                      __half* __restrict__ h, int n2) {
  int gw = (int)((blockIdx.x * blockDim.x + threadIdx.x) >> 6);
  if (gw >= n2) return;
  int lane = threadIdx.x & 63;
  int q = lane >> 4, l16 = lane & 15;
  int d = __builtin_nontemporal_load(deg_dst + gw);
  int end = __builtin_nontemporal_load(endp + gw);
  int start = end - d;
  const char* xb = (const char*)xw;
  __half2 z = __floats2half2_rn(0.f, 0.f);
  __half2 a0[4], a1[4], a2[4], a3[4];
#pragma unroll
  for (int k = 0; k < 4; ++k) { a0[k] = z; a1[k] = z; a2[k] = z; a3[k] = z; }
  for (int i = start + q; i < end; i += 16) {
    int i1 = i + 4, i2 = i + 8, i3 = i + 12;
    bool b1 = i1 < end, b2 = i2 < end, b3 = i3 < end;
    int r0 = __builtin_nontemporal_load(ssrc + i);
    int r1, r2, r3;
    if (b1) r1 = __builtin_nontemporal_load(ssrc + i1);
    if (b2) r2 = __builtin_nontemporal_load(ssrc + i2);
    if (b3) r3 = __builtin_nontemporal_load(ssrc + i3);
    uint4 u0 = *(const uint4*)(xb + r0 + l16 * 16);
    uint4 u1, u2, u3;
    if (b1) u1 = *(const uint4*)(xb + r1 + l16 * 16);
    if (b2) u2 = *(const uint4*)(xb + r2 + l16 * 16);
    if (b3) u3 = *(const uint4*)(xb + r3 + l16 * 16);
    {
      const __half2* p = (const __half2*)&u0;
#pragma unroll
      for (int k = 0; k < 4; ++k) a0[k] = __hadd2(a0[k], p[k]);
    }
    if (b1) {
      const __half2* p = (const __half2*)&u1;
#pragma unroll
      for (int k = 0; k < 4; ++k) a1[k] = __hadd2(a1[k], p[k]);
    }
    if (b2) {
      const __half2* p = (const __half2*)&u2;
#pragma unroll
      for (int k = 0; k < 4; ++k) a2[k] = __hadd2(a2[k], p[k]);
    }
    if (b3) {
      const __half2* p = (const __half2*)&u3;
#pragma unroll
      for (int k = 0; k < 4; ++k) a3[k] = __hadd2(a3[k], p[k]);
    }
  }
  float f[8];
#pragma unroll
  for (int k = 0; k < 4; ++k) {
    float2 x0 = __half22float2(a0[k]);
    float2 x1 = __half22float2(a1[k]);
    float2 x2 = __half22float2(a2[k]);
    float2 x3 = __half22float2(a3[k]);
    f[2 * k]     = (x0.x + x1.x) + (x2.x + x3.x);
    f[2 * k + 1] = (x0.y + x1.y) + (x2.y + x3.y);
  }
#pragma unroll
  for (int k = 0; k < 8; ++k) {
    f[k] += __shfl_xor(f[k], 16, 64);
    f[k] += __shfl_xor(f[k], 32, 64);
  }
  if (q == 0) {
    float invd = d > 0 ? rsqrtf((float)d) : 0.f;
    __half2 pk[4];
#pragma unroll
    for (int k = 0; k < 4; ++k)
      pk[k] = __floats2half2_rn(fmaxf(f[2 * k] * invd, 0.f),
                                fmaxf(f[2 * k + 1] * invd, 0.f));
    uint4 u;
    u.x = *(unsigned*)&pk[0]; u.y = *(unsigned*)&pk[1];
    u.z = *(unsigned*)&pk[2]; u.w = *(unsigned*)&pk[3];
    nt_store16((uint4*)(h + (size_t)gw * KC) + l16, u);
  }
}

// ---- link scorer: persistent quarter-waves, unroll x2, nt streams -------
__global__ void k_links(const __half* __restrict__ h,
                        const int* __restrict__ srcs, const int* __restrict__ dsts,
                        const float* __restrict__ Wp, const float* __restrict__ bp,
                        float* __restrict__ out, int L, int N) {
  int tid = blockIdx.x * blockDim.x + threadIdx.x;
  int lane = threadIdx.x & 63;
  int q = lane >> 4, l16 = lane & 15;
  int gq = (tid >> 6) * 4 + q;
  int nq = (int)((gridDim.x * blockDim.x) >> 6) * 4;
  float w8[8];
#pragma unroll
  for (int k = 0; k < 4; ++k) {
    float4 w = ((const float4*)Wp)[l16 * 4 + k];
    w8[2 * k] = w.x + w.y; w8[2 * k + 1] = w.z + w.w;
  }
  float bs = bp[0] + bp[1];
  const __half* hu = h + (size_t)N * KC;
  for (int li = gq; li < L; li += 2 * nq) {
    int li2 = li + nq;
    bool h2 = li2 < L;
    int s1 = __builtin_nontemporal_load(srcs + li);
    int d1 = __builtin_nontemporal_load(dsts + li);
    int s2 = 0, d2 = 0;
    if (h2) {
      s2 = __builtin_nontemporal_load(srcs + li2);
      d2 = __builtin_nontemporal_load(dsts + li2);
    }
    uint4 ua1 = ((const uint4*)(hu + (size_t)s1 * KC))[l16];
    uint4 ub1 = ((const uint4*)(h + (size_t)d1 * KC))[l16];
    uint4 ua2, ub2;
    if (h2) {
      ua2 = ((const uint4*)(hu + (size_t)s2 * KC))[l16];
      ub2 = ((const uint4*)(h + (size_t)d2 * KC))[l16];
    }
    float acc1 = 0.f, acc2 = 0.f;
    {
      const __half2* pa = (const __half2*)&ua1;
      const __half2* pb = (const __half2*)&ub1;
#pragma unroll
      for (int k = 0; k < 4; ++k) {
        float2 fa = __half22float2(pa[k]);
        float2 fb = __half22float2(pb[k]);
        acc1 += fa.x * fb.x * w8[2 * k] + fa.y * fb.y * w8[2 * k + 1];
      }
    }
    if (h2) {
      const __half2* pa = (const __half2*)&ua2;
      const __half2* pb = (const __half2*)&ub2;
#pragma unroll
      for (int k = 0; k < 4; ++k) {
        float2 fa = __half22float2(pa[k]);
        float2 fb = __half22float2(pb[k]);
        acc2 += fa.x * fb.x * w8[2 * k] + fa.y * fb.y * w8[2 * k + 1];
      }
    }
#pragma unroll
    for (int off = 8; off; off >>= 1) {
      acc1 += __shfl_xor(acc1, off, 64);
      acc2 += __shfl_xor(acc2, off, 64);
    }
    if (l16 == 0) {
      __builtin_nontemporal_store(acc1 + bs, out + li);
      if (h2) __builtin_nontemporal_store(acc2 + bs, out + li2);
    }
  }
}

// ========================================================================
extern "C" void kernel_launch(void* const* d_in, const int* in_sizes, int n_in,
                              void* d_out, int out_size, void* d_ws, size_t ws_size,
                              hipStream_t stream) {
  const float* x_user = (const float*)d_in[0];
  const float* x_item = (const float*)d_in[1];
  const int*   edge_ui = (const int*)d_in[2];
  const int*   edge_iu = (const int*)d_in[3];
  const int*   elab    = (const int*)d_in[4];
  const float* p_ui   = (const float*)d_in[5];
  const float* W0_ui  = (const float*)d_in[6];
  const float* Wih_ui = (const float*)d_in[7];
  const float* Whh_ui = (const float*)d_in[8];
  const float* bih_ui = (const float*)d_in[9];
  const float* bhh_ui = (const float*)d_in[10];
  const float* p_iu   = (const float*)d_in[11];
  const float* W0_iu  = (const float*)d_in[12];
  const float* Wih_iu = (const float*)d_in[13];
  const float* Whh_iu = (const float*)d_in[14];
  const float* bih_iu = (const float*)d_in[15];
  const float* bhh_iu = (const float*)d_in[16];
  const float* W_post = (const float*)d_in[17];
  const float* b_post = (const float*)d_in[18];
  const int N = in_sizes[0] / KC;
  const int E = in_sizes[2] / 2;
  const int L = in_sizes[4] / 2;
  const int N2 = 2 * N;
  const int NBC = (N2 + CSZ - 1) >> CBITS;      // 157 coarse buckets
  const int chunk = (((2 * E + NBLK - 1) / NBLK) + 3) & ~3;  // 980, mult of 4
  const int NTOT = NBC * NBLK;                  // 321536 per segment
  const int SCB = (NTOT + 1023) / 1024;         // 314 scan blocks / segment

  char* wsp = (char*)d_ws;
  auto carve = [&](size_t bytes) -> void* {
    void* p = (void*)wsp;
    wsp += (bytes + 255) & ~(size_t)255;
    return p;
  };
  // zeroed region: hist[2*65536] | ctrl[16 u32]
  const size_t histB = 2 * 65536 * 4;
  const size_t zBytes = histB + 256;
  char*     zbase    = (char*)carve(zBytes);
  unsigned* hist     = (unsigned*)zbase;
  unsigned* ctrl     = (unsigned*)(zbase + histB);
  // non-zeroed scratch
  int*      deg_src  = (int*)carve((size_t)N2 * 4);
  __half*   x16      = (__half*)carve((size_t)N2 * KC * 2);
  __half*   xw       = (__half*)carve((size_t)N2 * KC * 2);
  __half*   h        = (__half*)carve((size_t)N2 * KC * 2);  // [h_item | h_user]
  float*    scores   = (float*)carve((size_t)N2 * 4);
  int*      cand_idx = (int*)carve(2 * 2048 * 4);
  float*    cand_val = (float*)carve(2 * 2048 * 4);
  int*      top_idx  = (int*)carve(2 * KC * 4);
  float*    top_tanh = (float*)carve(2 * KC * 4);
  __half*   Wt16     = (__half*)carve(2 * KC * KC * 2);
  unsigned* cnts     = (unsigned*)carve((size_t)2 * NTOT * 4);  // [dst | src]
  unsigned* sc       = (unsigned*)carve((size_t)2 * NTOT * 4);
  unsigned* bsum     = (unsigned*)carve((size_t)2 * SCB * 4);
  unsigned* recsD    = (unsigned*)carve((size_t)2 * E * 4);
  unsigned short* recsS = (unsigned short*)carve((size_t)2 * E * 2);
  int*      ssrc     = (int*)carve((size_t)2 * E * 4);
  int*      deg_dst  = (int*)carve((size_t)N2 * 4);
  int*      endp     = (int*)carve((size_t)N2 * 4);

  hipMemsetAsync(zbase, 0, zBytes, stream);

  // M1: dst+src coarse counts (int4 quads) || scores + x16 (unroll x2)
  const int SBLK = 2048;
  m1_cnt_scores<<<NBLK + SBLK, 256, 0, stream>>>(edge_ui, edge_iu, cnts,
                                                 x_user, x_item, p_ui, p_iu,
                                                 scores, hist, x16,
                                                 E, N, NBC, chunk, NTOT);
  // M2: threshold bin || scan1 (two segments, shfl scan)
  m2_thresh_scan1<<<2 + 2 * SCB, 1024, 0, stream>>>(cnts, sc, bsum, hist, ctrl,
                                                    NTOT, NBC, SCB);
  // M3: scan2 || compact candidates
  m3_scan2_compact<<<2 + (N2 + 511) / 512, 512, 0, stream>>>(bsum, SCB, scores, ctrl,
                                                             cand_idx, cand_val, N);
  // M4: exact top-k || fused dst+src partition (int4 quads)
  m4_topk_part<<<2 + NBLK, 256, 0, stream>>>(edge_ui, edge_iu, cnts, sc, bsum,
                                             recsD, recsS, ctrl, cand_idx, cand_val,
                                             p_ui, p_iu, top_idx, top_tanh,
                                             E, N, NBC, chunk, NTOT, SCB);
  // M5: refine (dst CSR + src degrees) || GRU weight evolution
  m5_refine_gru<<<2 * NBC + 2 * KC, 1024, 0, stream>>>(sc, bsum, recsD, recsS, ssrc,
                                                       deg_dst, endp, deg_src,
                                                       x_user, x_item, top_idx, top_tanh,
                                                       W0_ui, W0_iu, Wih_ui, Wih_iu,
                                                       Whh_ui, Whh_iu, bih_ui, bih_iu,
                                                       bhh_ui, bhh_iu, Wt16,
                                                       E, NBC, N2, NTOT, SCB);
  // GCN: MFMA gemm (inv_s fused, fp16 out) then gather-aggregate
  k_gemm<<<N2 / 64, 256, 0, stream>>>(x16, Wt16, deg_src, xw, N);
  k_agg<<<(N2 + 3) / 4, 256, 0, stream>>>(xw, ssrc, endp, deg_dst, h, N2);
  // Link scorer
  k_links<<<2048, 256, 0, stream>>>(h, elab, elab + L, W_post, b_post,
                                    (float*)d_out, L, N);
}

// Round 10
// 386.228 us; speedup vs baseline: 1.0164x; 1.0164x over previous
//
#include <hip/hip_runtime.h>
#include <hip/hip_fp16.h>

constexpr int KC    = 128;    // channels
constexpr int NBLK  = 2048;   // count/partition blocks (8/CU)
constexpr int CAPA  = 1024;   // per-block edge chunk cap (chunk = 980)
constexpr int CBITS = 10;     // coarse bucket = 1024 nodes
constexpr int CSZ   = 1 << CBITS;
constexpr int NBCM  = 192;    // static max coarse buckets (157 actual)

using half8   = __attribute__((ext_vector_type(8))) _Float16;
using float4v = __attribute__((ext_vector_type(4))) float;

// ---------------------------------------------------------------- helpers
__device__ __forceinline__ unsigned fkey(float s) {
  unsigned u = __float_as_uint(s);
  return (u & 0x80000000u) ? ~u : (u | 0x80000000u);
}

// ==== M1: blocks [0,NBLK) = dst+src coarse counts ; rest = scores ========
__global__ __launch_bounds__(256) void m1_cnt_scores(
    const int* __restrict__ eui, const int* __restrict__ eiu,
    unsigned* __restrict__ cnts,
    const float* __restrict__ xu, const float* __restrict__ xi,
    const float* __restrict__ pu, const float* __restrict__ pi,
    float* __restrict__ scores, unsigned* __restrict__ hist,
    __half* __restrict__ x16,
    int E, int N, int NBC, int chunk, int NTOT) {
  __shared__ unsigned hD[4 * NBCM], hS[4 * NBCM];
  int t = threadIdx.x;
  if (blockIdx.x < NBLK) {
    // ---- count role: 4 edges/thread, int4 loads, one fat iteration ----
    int blk = blockIdx.x, w = t >> 6;
    for (int b = t; b < 4 * NBCM; b += 256) { hD[b] = 0; hS[b] = 0; }
    __syncthreads();
    int lo = blk * chunk, hi = min(2 * E, lo + chunk);
    int i = lo + t * 4;
    unsigned bw = w * NBCM;
    if (i + 3 < hi) {
      int rel = i >= E;
      int j = i - rel * E;
      if (rel == (int)(i + 3 >= E) && !(j & 3)) {
        const int* e = rel ? eiu : eui;
        int4 s4 = *(const int4*)(e + j);
        int4 d4 = *(const int4*)(e + E + j);
        int rb = rel * N;
        atomicAdd(&hD[bw + ((rb + d4.x) >> CBITS)], 1u);
        atomicAdd(&hD[bw + ((rb + d4.y) >> CBITS)], 1u);
        atomicAdd(&hD[bw + ((rb + d4.z) >> CBITS)], 1u);
        atomicAdd(&hD[bw + ((rb + d4.w) >> CBITS)], 1u);
        atomicAdd(&hS[bw + ((rb + s4.x) >> CBITS)], 1u);
        atomicAdd(&hS[bw + ((rb + s4.y) >> CBITS)], 1u);
        atomicAdd(&hS[bw + ((rb + s4.z) >> CBITS)], 1u);
        atomicAdd(&hS[bw + ((rb + s4.w) >> CBITS)], 1u);
      } else {
#pragma unroll
        for (int k = 0; k < 4; ++k) {
          int ii = i + k;
          int rl = ii >= E;
          const int* e = rl ? eiu : eui;
          int jj = ii - rl * E;
          atomicAdd(&hD[bw + ((rl * N + e[E + jj]) >> CBITS)], 1u);
          atomicAdd(&hS[bw + ((rl * N + e[jj]) >> CBITS)], 1u);
        }
      }
    } else {
#pragma unroll
      for (int k = 0; k < 4; ++k) {
        int ii = i + k;
        if (ii < hi) {
          int rl = ii >= E;
          const int* e = rl ? eiu : eui;
          int jj = ii - rl * E;
          atomicAdd(&hD[bw + ((rl * N + e[E + jj]) >> CBITS)], 1u);
          atomicAdd(&hS[bw + ((rl * N + e[jj]) >> CBITS)], 1u);
        }
      }
    }
    __syncthreads();
    for (int b = t; b < NBC; b += 256) {
      cnts[(size_t)blk * NBC + b] =
          hD[b] + hD[NBCM + b] + hD[2 * NBCM + b] + hD[3 * NBCM + b];
      cnts[(size_t)NTOT + (size_t)blk * NBC + b] =
          hS[b] + hS[NBCM + b] + hS[2 * NBCM + b] + hS[3 * NBCM + b];
    }
  } else {
    // ---- scores role: quarter-wave per row, unroll x2, grid-stride ----
    int qw = t >> 4;                 // quarter-wave index in block: 0..15
    int q  = t & 15;                 // lane within quarter
    int sgrid = (int)gridDim.x - NBLK;
    int stride = sgrid * 16;
    for (int gw = (blockIdx.x - NBLK) * 16 + qw; gw < 2 * N; gw += 2 * stride) {
      int gwB = gw + stride;
      bool hasB = gwB < 2 * N;
      int relA = gw >= N, rA = gw - relA * N;
      const float* xAp = relA ? xi : xu;
      const float* pAp = relA ? pi : pu;
      const float4* xrA = (const float4*)(xAp + (size_t)rA * KC);
      float4 a0 = xrA[q * 2], a1 = xrA[q * 2 + 1];
      float4 b0, b1;
      const float* pBp = pu;
      int relB = 0;
      if (hasB) {
        relB = gwB >= N;
        int rB = gwB - relB * N;
        const float* xBp = relB ? xi : xu;
        const float4* xrB = (const float4*)(xBp + (size_t)rB * KC);
        b0 = xrB[q * 2]; b1 = xrB[q * 2 + 1];
        pBp = relB ? pi : pu;
      }
      const float4* prA = (const float4*)pAp;
      float4 pa0 = prA[q * 2], pa1 = prA[q * 2 + 1];
      {
        __half2 h0 = __floats2half2_rn(a0.x, a0.y);
        __half2 h1 = __floats2half2_rn(a0.z, a0.w);
        __half2 h2 = __floats2half2_rn(a1.x, a1.y);
        __half2 h3 = __floats2half2_rn(a1.z, a1.w);
        uint4 u; u.x = *(unsigned*)&h0; u.y = *(unsigned*)&h1;
        u.z = *(unsigned*)&h2; u.w = *(unsigned*)&h3;
        ((uint4*)(x16 + (size_t)gw * KC))[q] = u;
      }
      float sA = a0.x * pa0.x + a0.y * pa0.y + a0.z * pa0.z + a0.w * pa0.w
               + a1.x * pa1.x + a1.y * pa1.y + a1.z * pa1.z + a1.w * pa1.w;
      float sB = 0.f;
      if (hasB) {
        const float4* prB = (const float4*)pBp;
        float4 pb0 = prB[q * 2], pb1 = prB[q * 2 + 1];
        __half2 h0 = __floats2half2_rn(b0.x, b0.y);
        __half2 h1 = __floats2half2_rn(b0.z, b0.w);
        __half2 h2 = __floats2half2_rn(b1.x, b1.y);
        __half2 h3 = __floats2half2_rn(b1.z, b1.w);
        uint4 u; u.x = *(unsigned*)&h0; u.y = *(unsigned*)&h1;
        u.z = *(unsigned*)&h2; u.w = *(unsigned*)&h3;
        ((uint4*)(x16 + (size_t)gwB * KC))[q] = u;
        sB = b0.x * pb0.x + b0.y * pb0.y + b0.z * pb0.z + b0.w * pb0.w
           + b1.x * pb1.x + b1.y * pb1.y + b1.z * pb1.z + b1.w * pb1.w;
      }
#pragma unroll
      for (int off = 8; off; off >>= 1) {
        sA += __shfl_xor(sA, off, 64);
        sB += __shfl_xor(sB, off, 64);
      }
      if (q == 0) {
        scores[gw] = sA;
        atomicAdd(&hist[relA * 65536 + (fkey(sA) >> 16)], 1u);
        if (hasB) {
          scores[gwB] = sB;
          atomicAdd(&hist[relB * 65536 + (fkey(sB) >> 16)], 1u);
        }
      }
    }
  }
}

// ==== M2: blocks 0,1 = threshold bin ; rest = scan1 (shfl scan) ==========
__global__ __launch_bounds__(1024) void m2_thresh_scan1(
    const unsigned* __restrict__ cnts, unsigned* __restrict__ sc,
    unsigned* __restrict__ bsum, const unsigned* __restrict__ hist,
    unsigned* __restrict__ ctrl, int NTOT, int NBC, int SCB) {
  __shared__ __align__(16) unsigned smem[1024 + 64 + 2];
  int t = threadIdx.x;
  if (blockIdx.x < 2) {
    // ---- k_thresh role ----
    const unsigned* h = hist + blockIdx.x * 65536;
    unsigned* c = ctrl + blockIdx.x * 8;
    unsigned* csum = smem;
    unsigned* bs = smem + 1024;
    unsigned s = 0;
    int hi = 65536 - 64 * t;
    for (int b = hi - 64; b < hi; ++b) s += h[b];
    csum[t] = s;
    __syncthreads();
    for (int off = 1; off < 1024; off <<= 1) {
      unsigned add = (t >= off) ? csum[t - off] : 0;
      __syncthreads();
      csum[t] += add;
      __syncthreads();
    }
    unsigned above = (t == 0) ? 0u : csum[t - 1];
    if (csum[t] >= 128u && above < 128u) { smem[1088] = (unsigned)t; smem[1089] = above; }
    __syncthreads();
    int chi = 65536 - 64 * (int)smem[1088];
    unsigned s_above = smem[1089];
    if (t < 64) bs[t] = h[chi - 1 - t];
    __syncthreads();
    if (t < 64) {
      unsigned v = bs[t], cum = v;
#pragma unroll
      for (int off = 1; off < 64; off <<= 1) {
        unsigned u = __shfl_up(cum, off, 64);
        if (t >= off) cum += u;
      }
      unsigned prev = cum - v;
      if (s_above + cum >= 128u && s_above + prev < 128u)
        c[0] = (unsigned)(chi - 1 - t);
    }
  } else {
    // ---- scan1 role: bucket-major reorder on read, wave-shfl scan ----
    unsigned* wsum = smem;                       // 16 partials
    int vb = blockIdx.x - 2;
    int seg = vb / SCB, lb = vb % SCB;
    int li = lb * 1024 + t;
    unsigned v = 0;
    if (li < NTOT) {
      int b = li >> 11, blk = li & (NBLK - 1);   // li = b*NBLK + blk
      v = cnts[(size_t)seg * NTOT + (size_t)blk * NBC + b];
    }
    unsigned inc = v;
#pragma unroll
    for (int off = 1; off < 64; off <<= 1) {
      unsigned u = __shfl_up(inc, off, 64);
      if ((t & 63) >= off) inc += u;
    }
    int w = t >> 6;
    if ((t & 63) == 63) wsum[w] = inc;
    __syncthreads();
    unsigned wbase = 0;
#pragma unroll
    for (int j = 0; j < 16; ++j) if (j < w) wbase += wsum[j];
    if (li < NTOT) sc[(size_t)seg * NTOT + li] = wbase + inc - v;
    if (t == 1023) bsum[vb] = wbase + inc;
  }
}

// ==== M3: blocks 0,1 = scan2 (shfl) ; rest = compact =====================
__global__ __launch_bounds__(512) void m3_scan2_compact(
    unsigned* __restrict__ bsum, int nb,
    const float* __restrict__ scores, unsigned* __restrict__ ctrl,
    int* __restrict__ cand_idx, float* __restrict__ cand_val, int N) {
  __shared__ unsigned wsum[8];
  if (blockIdx.x < 2) {
    unsigned* bs = bsum + blockIdx.x * nb;
    int t = threadIdx.x;
    unsigned v = (t < nb) ? bs[t] : 0;
    unsigned inc = v;
#pragma unroll
    for (int off = 1; off < 64; off <<= 1) {
      unsigned u = __shfl_up(inc, off, 64);
      if ((t & 63) >= off) inc += u;
    }
    int w = t >> 6;
    if ((t & 63) == 63) wsum[w] = inc;
    __syncthreads();
    unsigned wbase = 0;
#pragma unroll
    for (int j = 0; j < 8; ++j) if (j < w) wbase += wsum[j];
    if (t < nb) bs[t] = wbase + inc - v;
  } else {
    int i = (blockIdx.x - 2) * 512 + threadIdx.x;
    if (i >= 2 * N) return;
    int rel = i >= N;
    float s = scores[i];
    if ((fkey(s) >> 16) >= ctrl[rel * 8]) {
      unsigned pos = atomicAdd(&ctrl[rel * 8 + 1], 1u);
      if (pos < 2048u) {
        cand_idx[rel * 2048 + pos] = i - rel * N;
        cand_val[rel * 2048 + pos] = s;
      }
    }
  }
}

// ==== M4: blocks 0,1 = exact top-k ; rest = fused dst+src partition ======
__global__ __launch_bounds__(256) void m4_topk_part(
    const int* __restrict__ eui, const int* __restrict__ eiu,
    const unsigned* __restrict__ cnts, const unsigned* __restrict__ sc,
    const unsigned* __restrict__ bsum,
    unsigned* __restrict__ recsD, unsigned short* __restrict__ recsS,
    const unsigned* __restrict__ ctrl,
    const int* __restrict__ cand_idx, const float* __restrict__ cand_val,
    const float* __restrict__ pu, const float* __restrict__ pi,
    int* __restrict__ top_idx, float* __restrict__ top_tanh,
    int E, int N, int NBC, int chunk, int NTOT, int SCB) {
  __shared__ __align__(16) char smem[16896];
  int t = threadIdx.x;
  if (blockIdx.x < 2) {
    // ---- k_topk role ----
    float* vals = (float*)smem;                 // 8192
    int*   idxs = (int*)(smem + 8192);          // 8192
    float* red  = (float*)(smem + 16384);       // 512
    int rel = blockIdx.x;
    const float* p = rel ? pi : pu;
    int n = (int)ctrl[rel * 8 + 1]; if (n > 2048) n = 2048;
    for (int i = t; i < n; i += 256) {
      vals[i] = cand_val[rel * 2048 + i];
      idxs[i] = cand_idx[rel * 2048 + i];
    }
    if (t < 128) { float pv = p[t]; red[t] = pv * pv; }
    __syncthreads();
    for (int off = 64; off; off >>= 1) {
      if (t < off) red[t] += red[t + off];
      __syncthreads();
    }
    float pn = sqrtf(red[0]) + 1e-16f;
    for (int c = t; c < n; c += 256) {
      float v = vals[c]; int id = idxs[c];
      int rank = 0;
      for (int j = 0; j < n; ++j) {
        float vj = vals[j];
        rank += (vj > v) || (vj == v && idxs[j] < id);
      }
      if (rank < KC) {
        top_idx[rel * KC + rank] = id;
        top_tanh[rel * KC + rank] = tanhf(v / pn);
      }
    }
  } else {
    // ---- k_part role (dst + src, LDS-staged, shfl scans, quad loads) ----
    unsigned* wsumD  = (unsigned*)smem;              // 16
    unsigned* wsumS  = (unsigned*)(smem + 64);       // 16
    unsigned* curD   = (unsigned*)(smem + 1024);     // 1024
    unsigned* curS   = (unsigned*)(smem + 2048);     // 1024
    unsigned* deltaD = (unsigned*)(smem + 3072);     // 1024
    unsigned* deltaS = (unsigned*)(smem + 4096);     // 1024
    unsigned* stageD = (unsigned*)(smem + 5120);     // 4096
    unsigned short* stageS = (unsigned short*)(smem + 9216);   // 2048
    unsigned char* bktD = (unsigned char*)(smem + 11264);      // 1024
    unsigned char* bktS = (unsigned char*)(smem + 12288);      // 1024
    int blk = blockIdx.x - 2;
    int lane = t & 63, w = t >> 6;
    // dst + src exclusive scans, one shared barrier
    unsigned vD = (t < NBC) ? cnts[(size_t)blk * NBC + t] : 0;
    unsigned vS = (t < NBC) ? cnts[(size_t)NTOT + (size_t)blk * NBC + t] : 0;
    unsigned incD = vD, incS = vS;
#pragma unroll
    for (int off = 1; off < 64; off <<= 1) {
      unsigned uD = __shfl_up(incD, off, 64);
      unsigned uS = __shfl_up(incS, off, 64);
      if (lane >= off) { incD += uD; incS += uS; }
    }
    if (lane == 63) { wsumD[w] = incD; wsumS[w] = incS; }
    __syncthreads();
    unsigned wbD = 0, wbS = 0;
#pragma unroll
    for (int j = 0; j < 4; ++j) if (j < w) { wbD += wsumD[j]; wbS += wsumS[j]; }
    if (t < NBC) {
      unsigned excD = wbD + incD - vD;
      curD[t] = excD;
      int li = t * NBLK + blk;
      deltaD[t] = sc[li] + bsum[li >> 10] - excD;
      unsigned excS = wbS + incS - vS;
      curS[t] = excS;
      deltaS[t] = sc[NTOT + li] + bsum[SCB + (li >> 10)] - excS;
    }
    __syncthreads();
    int lo = blk * chunk, hi = min(2 * E, lo + chunk);
    int i = lo + t * 4;
    bool quad = false;
    int relq = 0, jq = 0;
    if (i + 3 < hi) {
      relq = i >= E;
      jq = i - relq * E;
      quad = (relq == (int)(i + 3 >= E)) && !(jq & 3);
    }
    if (quad) {
      const int* e = relq ? eiu : eui;
      int4 s4 = *(const int4*)(e + jq);
      int4 d4 = *(const int4*)(e + E + jq);
      int rb = relq * N;
      int ss[4] = {s4.x, s4.y, s4.z, s4.w};
      int dd[4] = {d4.x, d4.y, d4.z, d4.w};
#pragma unroll
      for (int k = 0; k < 4; ++k) {
        int src_g = rb + ss[k];
        int dst_g = rb + dd[k];
        int bD = dst_g >> CBITS;
        unsigned pD = atomicAdd(&curD[bD], 1u);
        stageD[pD] = (unsigned)src_g | ((unsigned)(dst_g & (CSZ - 1)) << 18);
        bktD[pD] = (unsigned char)bD;
        int bS = src_g >> CBITS;
        unsigned pS = atomicAdd(&curS[bS], 1u);
        stageS[pS] = (unsigned short)(src_g & (CSZ - 1));
        bktS[pS] = (unsigned char)bS;
      }
    } else {
#pragma unroll
      for (int k = 0; k < 4; ++k) {
        int ii = i + k;
        if (ii < hi) {
          int rl = ii >= E;
          const int* e = rl ? eiu : eui;
          int jj = ii - rl * E;
          int src_g = rl * N + e[jj];
          int dst_g = rl * N + e[E + jj];
          int bD = dst_g >> CBITS;
          unsigned pD = atomicAdd(&curD[bD], 1u);
          stageD[pD] = (unsigned)src_g | ((unsigned)(dst_g & (CSZ - 1)) << 18);
          bktD[pD] = (unsigned char)bD;
          int bS = src_g >> CBITS;
          unsigned pS = atomicAdd(&curS[bS], 1u);
          stageS[pS] = (unsigned short)(src_g & (CSZ - 1));
          bktS[pS] = (unsigned char)bS;
        }
      }
    }
    __syncthreads();
    int cnt = hi - lo;
    for (int j = t; j < cnt; j += 256) {
      recsD[deltaD[bktD[j]] + j] = stageD[j];
      recsS[deltaS[bktS[j]] + j] = stageS[j];
    }
  }
}

// ==== M5: [0,NBC)=dst CSR refine ; [NBC,2NBC)=src degrees ; rest=GRU =====
__global__ __launch_bounds__(1024) void m5_refine_gru(
    const unsigned* __restrict__ sc, const unsigned* __restrict__ bsum,
    const unsigned* __restrict__ recsD, const unsigned short* __restrict__ recsS,
    int* __restrict__ ssrc, int* __restrict__ deg_dst, int* __restrict__ endp,
    int* __restrict__ deg_src,
    const float* __restrict__ xu, const float* __restrict__ xi,
    const int* __restrict__ top_idx, const float* __restrict__ top_tanh,
    const float* __restrict__ W0u, const float* __restrict__ W0i,
    const float* __restrict__ Wihu, const float* __restrict__ Wihi,
    const float* __restrict__ Whhu, const float* __restrict__ Whhi,
    const float* __restrict__ bihu, const float* __restrict__ bihi,
    const float* __restrict__ bhhu, const float* __restrict__ bhhi,
    __half* __restrict__ Wt,
    int E, int NBC, int N2, int NTOT, int SCB) {
  __shared__ __align__(16) char smem[8256];
  int t = threadIdx.x;
  if ((int)blockIdx.x < NBC) {
    // ---- dst refine: per-bucket histogram -> scan -> scatter ----
    unsigned* hist = (unsigned*)smem;            // 4096
    unsigned* cur  = (unsigned*)(smem + 4096);   // 4096
    unsigned* t16  = (unsigned*)(smem + 8192);   // 64
    int c = blockIdx.x;
    int liLo = c * NBLK;
    int lo = (int)(sc[liLo] + bsum[liLo >> 10]);
    int hi;
    if (c + 1 < NBC) {
      int liHi = (c + 1) * NBLK;
      hi = (int)(sc[liHi] + bsum[liHi >> 10]);
    } else hi = 2 * E;
    hist[t] = 0;
    __syncthreads();
    for (int j = lo + t; j < hi; j += 1024)
      atomicAdd(&hist[recsD[j] >> 18], 1u);
    __syncthreads();
    // exclusive scan over CSZ=1024 entries, one per thread
    unsigned v = hist[t];
    unsigned inc = v;
#pragma unroll
    for (int off = 1; off < 64; off <<= 1) {
      unsigned u = __shfl_up(inc, off, 64);
      if ((t & 63) >= off) inc += u;
    }
    int w = t >> 6;
    if ((t & 63) == 63) t16[w] = inc;
    __syncthreads();
    unsigned wbase = 0;
    for (int j = 0; j < 16; ++j) if (j < w) wbase += t16[j];
    unsigned exc = wbase + inc - v;
    cur[t] = exc;
    int node = c * CSZ + t;
    if (node < N2) {
      deg_dst[node] = (int)v;
      endp[node] = lo + (int)(exc + v);
    }
    __syncthreads();
    // placement; ssrc stores BYTE offsets into xw (src * 256)
    for (int j = lo + t; j < hi; j += 1024) {
      unsigned rec = recsD[j];
      unsigned pos = atomicAdd(&cur[rec >> 18], 1u);
      ssrc[lo + (int)pos] = (int)((rec & 0x3FFFFu) << 8);
    }
  } else if ((int)blockIdx.x < 2 * NBC) {
    // ---- src refine: per-bucket histogram -> degrees ----
    unsigned* hist = (unsigned*)smem;            // 4096
    int c = blockIdx.x - NBC;
    int liLo = c * NBLK;
    int lo = (int)(sc[NTOT + liLo] + bsum[SCB + (liLo >> 10)]);
    int hi;
    if (c + 1 < NBC) {
      int liHi = (c + 1) * NBLK;
      hi = (int)(sc[NTOT + liHi] + bsum[SCB + (liHi >> 10)]);
    } else hi = 2 * E;
    hist[t] = 0;
    __syncthreads();
    for (int j = lo + t; j < hi; j += 1024)
      atomicAdd(&hist[(unsigned)recsS[j]], 1u);
    __syncthreads();
    int node = c * CSZ + t;
    if (node < N2) deg_src[node] = (int)hist[t];
  } else {
    // ---- k_gru role (first 128 threads active) ----
    int gb = blockIdx.x - 2 * NBC;
    int rel = gb >> 7, c = gb & 127;
    const float* x   = rel ? xi   : xu;
    const float* W0  = rel ? W0i  : W0u;
    const float* Wih = rel ? Wihi : Wihu;
    const float* Whh = rel ? Whhi : Whhu;
    const float* bih = rel ? bihi : bihu;
    const float* bhh = rel ? bhhi : bhhu;
    float* xt = (float*)smem;
    float* w0 = (float*)(smem + 512);
    if (t < KC) {
      xt[t] = x[(size_t)top_idx[rel * KC + c] * KC + t] * top_tanh[rel * KC + c];
      w0[t] = W0[c * KC + t];
    }
    __syncthreads();
    if (t >= KC) return;
    int k = t;
    float gir = bih[k], giz = bih[KC + k], gin = bih[2 * KC + k];
    float ghr = bhh[k], ghz = bhh[KC + k], ghn = bhh[2 * KC + k];
    const float* wr = Wih + (size_t)k * KC;
    const float* wz = Wih + (size_t)(KC + k) * KC;
    const float* wn = Wih + (size_t)(2 * KC + k) * KC;
    const float* vr = Whh + (size_t)k * KC;
    const float* vz = Whh + (size_t)(KC + k) * KC;
    const float* vn = Whh + (size_t)(2 * KC + k) * KC;
    for (int j = 0; j < KC; ++j) {
      float xj = xt[j], hj = w0[j];
      gir += xj * wr[j]; giz += xj * wz[j]; gin += xj * wn[j];
      ghr += hj * vr[j]; ghz += hj * vz[j]; ghn += hj * vn[j];
    }
    float r = 1.f / (1.f + expf(-(gir + ghr)));
    float z = 1.f / (1.f + expf(-(giz + ghz)));
    float nn = tanhf(gin + r * ghn);
    float w = (1.f - z) * nn + z * w0[k];
    Wt[(size_t)rel * KC * KC + (size_t)k * KC + c] = __float2half_rn(w);
  }
}

// ---- xw = x16 @ W via MFMA f16 16x16x32, inv_s fused, fp16 out ----------
__global__ __launch_bounds__(256) void k_gemm(const __half* __restrict__ x16,
                                              const __half* __restrict__ Wt,
                                              const int* __restrict__ deg_src,
                                              __half* __restrict__ xw, int N) {
  __shared__ __half Ws[KC * KC];        // 32 KB: Wt[n][k]
  __shared__ __half outs[64 * 136];     // 17 KB staging
  int rel = (blockIdx.x * 64) >= N;
  int t = threadIdx.x;
  const uint4* wg = (const uint4*)(Wt + (size_t)rel * KC * KC);
#pragma unroll
  for (int i = 0; i < 8; ++i)
    ((uint4*)Ws)[t + 256 * i] = wg[t + 256 * i];
  __syncthreads();
  int wid = t >> 6, lane = t & 63;
  int l15 = lane & 15, quad = lane >> 4;
  int row0 = blockIdx.x * 64 + wid * 16;
  half8 a[4];
  const __half* xrow = x16 + (size_t)(row0 + l15) * KC + quad * 8;
#pragma unroll
  for (int ks = 0; ks < 4; ++ks) a[ks] = *(const half8*)(xrow + ks * 32);
  float4v acc[8];
#pragma unroll
  for (int nt = 0; nt < 8; ++nt) {
    acc[nt] = (float4v){0.f, 0.f, 0.f, 0.f};
#pragma unroll
    for (int ks = 0; ks < 4; ++ks) {
      half8 b = *(const half8*)&Ws[(nt * 16 + l15) * KC + ks * 32 + quad * 8];
      acc[nt] = __builtin_amdgcn_mfma_f32_16x16x32_f16(a[ks], b, acc[nt], 0, 0, 0);
    }
  }
  float scv[4];
#pragma unroll
  for (int r = 0; r < 4; ++r) {
    int dg = deg_src[row0 + quad * 4 + r];
    scv[r] = dg > 0 ? rsqrtf((float)dg) : 0.f;
  }
  __half* ob = outs + (size_t)wid * 16 * 136;
#pragma unroll
  for (int nt = 0; nt < 8; ++nt)
#pragma unroll
    for (int r = 0; r < 4; ++r)
      ob[(quad * 4 + r) * 136 + nt * 16 + l15] = __float2half_rn(acc[nt][r] * scv[r]);
  __syncthreads();
  size_t gbase = (size_t)blockIdx.x * 64 * KC;
#pragma unroll
  for (int i = 0; i < 4; ++i) {
    int idx = t + 256 * i;
    int rr = idx >> 4, cc = idx & 15;
    *(uint4*)(xw + gbase + (size_t)rr * KC + cc * 8) =
        *(const uint4*)(outs + (size_t)rr * 136 + cc * 8);
  }
}

// ---- aggregation: quarter-wave, 4-deep predicated, byte-offset gather ---
__global__ void k_agg(const __half* __restrict__ xw, const int* __restrict__ ssrc,
                      const int* __restrict__ endp, const int* __restrict__ deg_dst,
                      __half* __restrict__ h, int n2) {
  int gw = (int)((blockIdx.x * blockDim.x + threadIdx.x) >> 6);
  if (gw >= n2) return;
  int lane = threadIdx.x & 63;
  int q = lane >> 4, l16 = lane & 15;
  int d = deg_dst[gw];
  int end = endp[gw], start = end - d;
  const char* xb = (const char*)xw;
  __half2 z = __floats2half2_rn(0.f, 0.f);
  __half2 a0[4], a1[4], a2[4], a3[4];
#pragma unroll
  for (int k = 0; k < 4; ++k) { a0[k] = z; a1[k] = z; a2[k] = z; a3[k] = z; }
  for (int i = start + q; i < end; i += 16) {
    int i1 = i + 4, i2 = i + 8, i3 = i + 12;
    bool b1 = i1 < end, b2 = i2 < end, b3 = i3 < end;
    int r0 = ssrc[i], r1, r2, r3;
    if (b1) r1 = ssrc[i1];
    if (b2) r2 = ssrc[i2];
    if (b3) r3 = ssrc[i3];
    uint4 u0 = *(const uint4*)(xb + r0 + l16 * 16);
    uint4 u1, u2, u3;
    if (b1) u1 = *(const uint4*)(xb + r1 + l16 * 16);
    if (b2) u2 = *(const uint4*)(xb + r2 + l16 * 16);
    if (b3) u3 = *(const uint4*)(xb + r3 + l16 * 16);
    {
      const __half2* p = (const __half2*)&u0;
#pragma unroll
      for (int k = 0; k < 4; ++k) a0[k] = __hadd2(a0[k], p[k]);
    }
    if (b1) {
      const __half2* p = (const __half2*)&u1;
#pragma unroll
      for (int k = 0; k < 4; ++k) a1[k] = __hadd2(a1[k], p[k]);
    }
    if (b2) {
      const __half2* p = (const __half2*)&u2;
#pragma unroll
      for (int k = 0; k < 4; ++k) a2[k] = __hadd2(a2[k], p[k]);
    }
    if (b3) {
      const __half2* p = (const __half2*)&u3;
#pragma unroll
      for (int k = 0; k < 4; ++k) a3[k] = __hadd2(a3[k], p[k]);
    }
  }
  float f[8];
#pragma unroll
  for (int k = 0; k < 4; ++k) {
    float2 x0 = __half22float2(a0[k]);
    float2 x1 = __half22float2(a1[k]);
    float2 x2 = __half22float2(a2[k]);
    float2 x3 = __half22float2(a3[k]);
    f[2 * k]     = (x0.x + x1.x) + (x2.x + x3.x);
    f[2 * k + 1] = (x0.y + x1.y) + (x2.y + x3.y);
  }
#pragma unroll
  for (int k = 0; k < 8; ++k) {
    f[k] += __shfl_xor(f[k], 16, 64);
    f[k] += __shfl_xor(f[k], 32, 64);
  }
  if (q == 0) {
    float invd = d > 0 ? rsqrtf((float)d) : 0.f;
    __half2 pk[4];
#pragma unroll
    for (int k = 0; k < 4; ++k)
      pk[k] = __floats2half2_rn(fmaxf(f[2 * k] * invd, 0.f),
                                fmaxf(f[2 * k + 1] * invd, 0.f));
    uint4 u;
    u.x = *(unsigned*)&pk[0]; u.y = *(unsigned*)&pk[1];
    u.z = *(unsigned*)&pk[2]; u.w = *(unsigned*)&pk[3];
    ((uint4*)(h + (size_t)gw * KC))[l16] = u;
  }
}

// ---- link scorer: persistent quarter-waves, unroll x2 -------------------
__global__ void k_links(const __half* __restrict__ h,
                        const int* __restrict__ srcs, const int* __restrict__ dsts,
                        const float* __restrict__ Wp, const float* __restrict__ bp,
                        float* __restrict__ out, int L, int N) {
  int tid = blockIdx.x * blockDim.x + threadIdx.x;
  int lane = threadIdx.x & 63;
  int q = lane >> 4, l16 = lane & 15;
  int gq = (tid >> 6) * 4 + q;
  int nq = (int)((gridDim.x * blockDim.x) >> 6) * 4;
  float w8[8];
#pragma unroll
  for (int k = 0; k < 4; ++k) {
    float4 w = ((const float4*)Wp)[l16 * 4 + k];
    w8[2 * k] = w.x + w.y; w8[2 * k + 1] = w.z + w.w;
  }
  float bs = bp[0] + bp[1];
  const __half* hu = h + (size_t)N * KC;
  for (int li = gq; li < L; li += 2 * nq) {
    int li2 = li + nq;
    bool h2 = li2 < L;
    int s1 = srcs[li], d1 = dsts[li];
    int s2 = 0, d2 = 0;
    if (h2) { s2 = srcs[li2]; d2 = dsts[li2]; }
    uint4 ua1 = ((const uint4*)(hu + (size_t)s1 * KC))[l16];
    uint4 ub1 = ((const uint4*)(h + (size_t)d1 * KC))[l16];
    uint4 ua2, ub2;
    if (h2) {
      ua2 = ((const uint4*)(hu + (size_t)s2 * KC))[l16];
      ub2 = ((const uint4*)(h + (size_t)d2 * KC))[l16];
    }
    float acc1 = 0.f, acc2 = 0.f;
    {
      const __half2* pa = (const __half2*)&ua1;
      const __half2* pb = (const __half2*)&ub1;
#pragma unroll
      for (int k = 0; k < 4; ++k) {
        float2 fa = __half22float2(pa[k]);
        float2 fb = __half22float2(pb[k]);
        acc1 += fa.x * fb.x * w8[2 * k] + fa.y * fb.y * w8[2 * k + 1];
      }
    }
    if (h2) {
      const __half2* pa = (const __half2*)&ua2;
      const __half2* pb = (const __half2*)&ub2;
#pragma unroll
      for (int k = 0; k < 4; ++k) {
        float2 fa = __half22float2(pa[k]);
        float2 fb = __half22float2(pb[k]);
        acc2 += fa.x * fb.x * w8[2 * k] + fa.y * fb.y * w8[2 * k + 1];
      }
    }
#pragma unroll
    for (int off = 8; off; off >>= 1) {
      acc1 += __shfl_xor(acc1, off, 64);
      acc2 += __shfl_xor(acc2, off, 64);
    }
    if (l16 == 0) {
      out[li] = acc1 + bs;
      if (h2) out[li2] = acc2 + bs;
    }
  }
}

// ========================================================================
extern "C" void kernel_launch(void* const* d_in, const int* in_sizes, int n_in,
                              void* d_out, int out_size, void* d_ws, size_t ws_size,
                              hipStream_t stream) {
  const float* x_user = (const float*)d_in[0];
  const float* x_item = (const float*)d_in[1];
  const int*   edge_ui = (const int*)d_in[2];
  const int*   edge_iu = (const int*)d_in[3];
  const int*   elab    = (const int*)d_in[4];
  const float* p_ui   = (const float*)d_in[5];
  const float* W0_ui  = (const float*)d_in[6];
  const float* Wih_ui = (const float*)d_in[7];
  const float* Whh_ui = (const float*)d_in[8];
  const float* bih_ui = (const float*)d_in[9];
  const float* bhh_ui = (const float*)d_in[10];
  const float* p_iu   = (const float*)d_in[11];
  const float* W0_iu  = (const float*)d_in[12];
  const float* Wih_iu = (const float*)d_in[13];
  const float* Whh_iu = (const float*)d_in[14];
  const float* bih_iu = (const float*)d_in[15];
  const float* bhh_iu = (const float*)d_in[16];
  const float* W_post = (const float*)d_in[17];
  const float* b_post = (const float*)d_in[18];
  const int N = in_sizes[0] / KC;
  const int E = in_sizes[2] / 2;
  const int L = in_sizes[4] / 2;
  const int N2 = 2 * N;
  const int NBC = (N2 + CSZ - 1) >> CBITS;      // 157 coarse buckets
  const int chunk = (((2 * E + NBLK - 1) / NBLK) + 3) & ~3;  // 980, mult of 4
  const int NTOT = NBC * NBLK;                  // 321536 per segment
  const int SCB = (NTOT + 1023) / 1024;         // 314 scan blocks / segment

  char* wsp = (char*)d_ws;
  auto carve = [&](size_t bytes) -> void* {
    void* p = (void*)wsp;
    wsp += (bytes + 255) & ~(size_t)255;
    return p;
  };
  // zeroed region: hist[2*65536] | ctrl[16 u32]
  const size_t histB = 2 * 65536 * 4;
  const size_t zBytes = histB + 256;
  char*     zbase    = (char*)carve(zBytes);
  unsigned* hist     = (unsigned*)zbase;
  unsigned* ctrl     = (unsigned*)(zbase + histB);
  // non-zeroed scratch
  int*      deg_src  = (int*)carve((size_t)N2 * 4);
  __half*   x16      = (__half*)carve((size_t)N2 * KC * 2);
  __half*   xw       = (__half*)carve((size_t)N2 * KC * 2);
  __half*   h        = (__half*)carve((size_t)N2 * KC * 2);  // [h_item | h_user]
  float*    scores   = (float*)carve((size_t)N2 * 4);
  int*      cand_idx = (int*)carve(2 * 2048 * 4);
  float*    cand_val = (float*)carve(2 * 2048 * 4);
  int*      top_idx  = (int*)carve(2 * KC * 4);
  float*    top_tanh = (float*)carve(2 * KC * 4);
  __half*   Wt16     = (__half*)carve(2 * KC * KC * 2);
  unsigned* cnts     = (unsigned*)carve((size_t)2 * NTOT * 4);  // [dst | src]
  unsigned* sc       = (unsigned*)carve((size_t)2 * NTOT * 4);
  unsigned* bsum     = (unsigned*)carve((size_t)2 * SCB * 4);
  unsigned* recsD    = (unsigned*)carve((size_t)2 * E * 4);
  unsigned short* recsS = (unsigned short*)carve((size_t)2 * E * 2);
  int*      ssrc     = (int*)carve((size_t)2 * E * 4);
  int*      deg_dst  = (int*)carve((size_t)N2 * 4);
  int*      endp     = (int*)carve((size_t)N2 * 4);

  hipMemsetAsync(zbase, 0, zBytes, stream);

  // M1: dst+src coarse counts (int4 quads) || scores + x16 (unroll x2)
  const int SBLK = 2048;
  m1_cnt_scores<<<NBLK + SBLK, 256, 0, stream>>>(edge_ui, edge_iu, cnts,
                                                 x_user, x_item, p_ui, p_iu,
                                                 scores, hist, x16,
                                                 E, N, NBC, chunk, NTOT);
  // M2: threshold bin || scan1 (two segments, shfl scan)
  m2_thresh_scan1<<<2 + 2 * SCB, 1024, 0, stream>>>(cnts, sc, bsum, hist, ctrl,
                                                    NTOT, NBC, SCB);
  // M3: scan2 || compact candidates
  m3_scan2_compact<<<2 + (N2 + 511) / 512, 512, 0, stream>>>(bsum, SCB, scores, ctrl,
                                                             cand_idx, cand_val, N);
  // M4: exact top-k || fused dst+src partition (int4 quads)
  m4_topk_part<<<2 + NBLK, 256, 0, stream>>>(edge_ui, edge_iu, cnts, sc, bsum,
                                             recsD, recsS, ctrl, cand_idx, cand_val,
                                             p_ui, p_iu, top_idx, top_tanh,
                                             E, N, NBC, chunk, NTOT, SCB);
  // M5: refine (dst CSR + src degrees) || GRU weight evolution
  m5_refine_gru<<<2 * NBC + 2 * KC, 1024, 0, stream>>>(sc, bsum, recsD, recsS, ssrc,
                                                       deg_dst, endp, deg_src,
                                                       x_user, x_item, top_idx, top_tanh,
                                                       W0_ui, W0_iu, Wih_ui, Wih_iu,
                                                       Whh_ui, Whh_iu, bih_ui, bih_iu,
                                                       bhh_ui, bhh_iu, Wt16,
                                                       E, NBC, N2, NTOT, SCB);
  // GCN: MFMA gemm (inv_s fused, fp16 out) then gather-aggregate
  k_gemm<<<N2 / 64, 256, 0, stream>>>(x16, Wt16, deg_src, xw, N);
  k_agg<<<(N2 + 3) / 4, 256, 0, stream>>>(xw, ssrc, endp, deg_dst, h, N2);
  // Link scorer
  k_links<<<2048, 256, 0, stream>>>(h, elab, elab + L, W_post, b_post,
                                    (float*)d_out, L, N);
}